// Round 2
// baseline (248.279 us; speedup 1.0000x reference)
//
#include <hip/hip_runtime.h>
#include <hip/hip_bf16.h>

#define N_NODES 8192
#define N_EDGES 65536

// workspace layout (float offsets)
#define Z_OFF    0            // 8192
#define W2K_OFF  8192         // 16384
#define W2V_OFF  24576        // 16384
#define QD0_OFF  40960        // 131072
#define QD1_OFF  172032       // 393216
#define EXP_OFF  565248       // 65536
#define S_OFF    630784       // 65536
#define V_OFF    696320       // 4194304
// total = 4890624 floats = ~19.6 MiB

__device__ __forceinline__ float sus_f(float x) { return x > 0.f ? expf(-1.f / x) : 0.f; }
__device__ __forceinline__ float silu_f(float x) { return x / (1.f + expf(-x)); }

// K0: transpose Wk2/Wv2 (HID=16 x 1024) -> fp32 [o][h], folding 0.25 (W2/sqrt(HID))
// and a = 1/sqrt(2*MUL) from fctp.
__global__ void k_prep_w(const float* __restrict__ Wk2,
                         const float* __restrict__ Wv2,
                         float* __restrict__ w2k, float* __restrict__ w2v) {
    int t = blockIdx.x * blockDim.x + threadIdx.x;   // 16384
    int o = t >> 4, h = t & 15;
    const float SC = 0.25f * 0.17677669529663687f;   // 0.25 * 1/sqrt(32)
    w2k[t] = Wk2[h * 1024 + o] * SC;
    w2v[t] = Wv2[h * 1024 + o] * SC;
}

// K1: per-node qd0[j] = ad/4 * sum_i Wd0[i,j] (f0@Wq0)[i]
//     qd1[j,c] = ad/(4*sqrt3) * sum_i Wd1[i,j] (f1c@Wq1)[i]
__global__ __launch_bounds__(256) void k_prep_node(
    const float* __restrict__ f_in,
    const float* __restrict__ Wq0, const float* __restrict__ Wq1,
    const float* __restrict__ Wd0, const float* __restrict__ Wd1,
    float* __restrict__ qd0, float* __restrict__ qd1) {
    __shared__ float f0s[16][16];
    __shared__ float f1s[16][48];
    __shared__ float t0s[16][16];
    __shared__ float t1s[16][48];
    const int tid = threadIdx.x;
    const int j = tid & 15, ln = tid >> 4;
    const int n = blockIdx.x * 16 + ln;
    f0s[ln][j]         = f_in[n * 64 + j];
    f1s[ln][j * 3 + 0] = f_in[n * 64 + 16 + j * 3 + 0];
    f1s[ln][j * 3 + 1] = f_in[n * 64 + 16 + j * 3 + 1];
    f1s[ln][j * 3 + 2] = f_in[n * 64 + 16 + j * 3 + 2];
    __syncthreads();
    float t0 = 0.f, ta = 0.f, tb = 0.f, tc = 0.f;
#pragma unroll
    for (int p = 0; p < 16; ++p) {
        float wq0 = Wq0[p * 16 + j];
        float wq1 = Wq1[p * 16 + j];
        t0 += f0s[ln][p] * wq0;
        ta += f1s[ln][p * 3 + 0] * wq1;
        tb += f1s[ln][p * 3 + 1] * wq1;
        tc += f1s[ln][p * 3 + 2] * wq1;
    }
    t0s[ln][j] = t0;
    t1s[ln][j * 3 + 0] = ta; t1s[ln][j * 3 + 1] = tb; t1s[ln][j * 3 + 2] = tc;
    __syncthreads();
    float q0a = 0.f, qa = 0.f, qb = 0.f, qc = 0.f;
#pragma unroll
    for (int i = 0; i < 16; ++i) {
        float wd0 = Wd0[i * 16 + j];
        float wd1 = Wd1[i * 16 + j];
        q0a += t0s[ln][i] * wd0;
        qa  += t1s[ln][i * 3 + 0] * wd1;
        qb  += t1s[ln][i * 3 + 1] * wd1;
        qc  += t1s[ln][i * 3 + 2] * wd1;
    }
    const float S0 = 0.011048543456f;     // (1/sqrt(512))/4
    const float S1 = 0.0063788674817f;    // S0/sqrt(3)
    qd0[n * 16 + j] = q0a * S0;
    qd1[n * 48 + j * 3 + 0] = qa * S1;
    qd1[n * 48 + j * 3 + 1] = qb * S1;
    qd1[n * 48 + j * 3 + 2] = qc * S1;
}

__device__ __forceinline__ void wdot4(const float* __restrict__ wrow,
                                      const float (&hreg)[4][16], float (&t)[4]) {
    float w[16];
#pragma unroll
    for (int q = 0; q < 4; ++q) ((float4*)w)[q] = ((const float4*)wrow)[q];
#pragma unroll
    for (int ee = 0; ee < 4; ++ee) {
        float acc = 0.f;
#pragma unroll
        for (int h = 0; h < 16; ++h) acc += hreg[ee][h] * w[h];
        t[ee] = acc;
    }
}

// K2: per-edge heavy kernel. 64 edges per 256-thread block.
__global__ __launch_bounds__(256) void k_edge(
    const float* __restrict__ f_in, const float* __restrict__ evec,
    const int* __restrict__ esrc, const int* __restrict__ edst,
    const float* __restrict__ Wk1, const float* __restrict__ Wv1,
    const float* __restrict__ w2k, const float* __restrict__ w2v,
    const float* __restrict__ qd0, const float* __restrict__ qd1,
    float* __restrict__ zbuf, float* __restrict__ expbuf, float* __restrict__ vbuf) {
    __shared__ float s_rb[64][16];
    __shared__ float s_sh[64][4];   // sh1[0..2] = sqrt3*u, [3] = edge_cut
    __shared__ float s_x0[64][16];
    __shared__ float s_xs[64][16];  // sum_c x1[i][c]*u[c]  (the /sqrt3 folded)
    __shared__ float s_x1[64][48];
    __shared__ float s_hk[64][16];
    __shared__ float s_hv[64][16];

    const int tid = threadIdx.x;
    const int e0 = blockIdx.x * 64;

    // Phase A0: radial basis + geometry (4 threads per edge)
    {
        const int el = tid >> 2, q = tid & 3;
        const int e = e0 + el;
        float v0 = evec[e * 3 + 0];
        float v1 = evec[e * 3 + 1];
        float v2 = evec[e * 3 + 2];
        float r = sqrtf(v0 * v0 + v1 * v1 + v2 * v2);
        float rs = r * 3.4f;                       // r/step, step = 5/17
#pragma unroll
        for (int bb = 0; bb < 4; ++bb) {
            int b = q * 4 + bb;
            // rb = C*sqrt(NB) * sus(r/step - b) * sus(b+2 - r/step)
            s_rb[el][b] = 33.734292f * sus_f(rs - (float)b) * sus_f((float)(b + 2) - rs);
        }
        if (q == 0) {
            float inv = r > 0.f ? 1.f / r : 0.f;
            const float SQ3 = 1.7320508075688772f;
            s_sh[el][0] = SQ3 * v0 * inv;
            s_sh[el][1] = SQ3 * v1 * inv;
            s_sh[el][2] = SQ3 * v2 * inv;
            s_sh[el][3] = sus_f(10.f - 2.f * r);   // edge_cut
        }
    }
    __syncthreads();

    // Phase A1: hidden layers + x staging (16 threads per edge, 4 rounds)
    {
        const int j = tid & 15, slot = tid >> 4;
#pragma unroll
        for (int s = 0; s < 4; ++s) {
            const int el = slot * 4 + s;
            const int e = e0 + el;
            float aK = 0.f, aV = 0.f;
#pragma unroll
            for (int b = 0; b < 16; ++b) {
                float rbv = s_rb[el][b];
                aK += rbv * Wk1[b * 16 + j];
                aV += rbv * Wv1[b * 16 + j];
            }
            s_hk[el][j] = silu_f(aK * 0.25f);
            s_hv[el][j] = silu_f(aV * 0.25f);
            const int src = esrc[e];
            float x0 = f_in[src * 64 + j];
            float xa = f_in[src * 64 + 16 + j * 3 + 0];
            float xb = f_in[src * 64 + 16 + j * 3 + 1];
            float xc = f_in[src * 64 + 16 + j * 3 + 2];
            s_x0[el][j] = x0;
            s_x1[el][j * 3 + 0] = xa;
            s_x1[el][j * 3 + 1] = xb;
            s_x1[el][j * 3 + 2] = xc;
            s_xs[el][j] = (xa * s_sh[el][0] + xb * s_sh[el][1] + xc * s_sh[el][2]) * 0.57735026919f;
        }
    }
    __syncthreads();

    // Phase B: thread = (output col j, 4 edges). Weights streamed, h in regs.
    const int j = tid & 15, slot = tid >> 4;
    const int elb = slot * 4;
    float hreg[4][16];
    float a0[4], a1[4], aw[4][3];
    const float* wbase;

    // ---------------- K pass ----------------
#pragma unroll
    for (int ee = 0; ee < 4; ++ee)
#pragma unroll
        for (int h = 0; h < 16; ++h) hreg[ee][h] = s_hk[elb + ee][h];
#pragma unroll
    for (int ee = 0; ee < 4; ++ee) { a0[ee] = 0.f; a1[ee] = 0.f; aw[ee][0] = 0.f; aw[ee][1] = 0.f; aw[ee][2] = 0.f; }

    wbase = w2k + j * 16;
#pragma unroll 4
    for (int i = 0; i < 16; ++i) {            // b=0: o0 += w0 . x0
        float t[4]; wdot4(wbase + i * 256, hreg, t);
#pragma unroll
        for (int ee = 0; ee < 4; ++ee) a0[ee] += t[ee] * s_x0[elb + ee][i];
    }
#pragma unroll 4
    for (int i = 0; i < 16; ++i) {            // b=1: o0 += w1 . (x1 . u)
        float t[4]; wdot4(wbase + 4096 + i * 256, hreg, t);
#pragma unroll
        for (int ee = 0; ee < 4; ++ee) a0[ee] += t[ee] * s_xs[elb + ee][i];
    }
#pragma unroll 4
    for (int i = 0; i < 16; ++i) {            // b=2: t2 += w2 . x0 (outer with sh later)
        float t[4]; wdot4(wbase + 8192 + i * 256, hreg, t);
#pragma unroll
        for (int ee = 0; ee < 4; ++ee) a1[ee] += t[ee] * s_x0[elb + ee][i];
    }
#pragma unroll 4
    for (int i = 0; i < 16; ++i) {            // b=3: o1 += w3 . x1
        float t[4]; wdot4(wbase + 12288 + i * 256, hreg, t);
#pragma unroll
        for (int ee = 0; ee < 4; ++ee) {
            aw[ee][0] += t[ee] * s_x1[elb + ee][i * 3 + 0];
            aw[ee][1] += t[ee] * s_x1[elb + ee][i * 3 + 1];
            aw[ee][2] += t[ee] * s_x1[elb + ee][i * 3 + 2];
        }
    }
    // dot + softmax numerator
#pragma unroll
    for (int ee = 0; ee < 4; ++ee) {
        const int el = elb + ee;
        const int e = e0 + el;
        const int dst = edst[e];
        float sh0 = s_sh[el][0], sh1 = s_sh[el][1], sh2 = s_sh[el][2];
        float k1x = a1[ee] * sh0 + aw[ee][0];
        float k1y = a1[ee] * sh1 + aw[ee][1];
        float k1z = a1[ee] * sh2 + aw[ee][2];
        const float* q1p = qd1 + dst * 48 + j * 3;
        float dp = qd0[dst * 16 + j] * a0[ee] + q1p[0] * k1x + q1p[1] * k1y + q1p[2] * k1z;
        dp += __shfl_xor(dp, 1);
        dp += __shfl_xor(dp, 2);
        dp += __shfl_xor(dp, 4);
        dp += __shfl_xor(dp, 8);
        if (j == 0) {
            float ev = s_sh[el][3] * expf(dp);
            expbuf[e] = ev;
            atomicAdd(zbuf + dst, ev);
        }
    }

    // ---------------- V pass ----------------
#pragma unroll
    for (int ee = 0; ee < 4; ++ee)
#pragma unroll
        for (int h = 0; h < 16; ++h) hreg[ee][h] = s_hv[elb + ee][h];
#pragma unroll
    for (int ee = 0; ee < 4; ++ee) { a0[ee] = 0.f; a1[ee] = 0.f; aw[ee][0] = 0.f; aw[ee][1] = 0.f; aw[ee][2] = 0.f; }

    wbase = w2v + j * 16;
#pragma unroll 4
    for (int i = 0; i < 16; ++i) {
        float t[4]; wdot4(wbase + i * 256, hreg, t);
#pragma unroll
        for (int ee = 0; ee < 4; ++ee) a0[ee] += t[ee] * s_x0[elb + ee][i];
    }
#pragma unroll 4
    for (int i = 0; i < 16; ++i) {
        float t[4]; wdot4(wbase + 4096 + i * 256, hreg, t);
#pragma unroll
        for (int ee = 0; ee < 4; ++ee) a0[ee] += t[ee] * s_xs[elb + ee][i];
    }
#pragma unroll 4
    for (int i = 0; i < 16; ++i) {
        float t[4]; wdot4(wbase + 8192 + i * 256, hreg, t);
#pragma unroll
        for (int ee = 0; ee < 4; ++ee) a1[ee] += t[ee] * s_x0[elb + ee][i];
    }
#pragma unroll 4
    for (int i = 0; i < 16; ++i) {
        float t[4]; wdot4(wbase + 12288 + i * 256, hreg, t);
#pragma unroll
        for (int ee = 0; ee < 4; ++ee) {
            aw[ee][0] += t[ee] * s_x1[elb + ee][i * 3 + 0];
            aw[ee][1] += t[ee] * s_x1[elb + ee][i * 3 + 1];
            aw[ee][2] += t[ee] * s_x1[elb + ee][i * 3 + 2];
        }
    }
#pragma unroll
    for (int ee = 0; ee < 4; ++ee) {
        const int el = elb + ee;
        const int e = e0 + el;
        float sh0 = s_sh[el][0], sh1 = s_sh[el][1], sh2 = s_sh[el][2];
        float* vp = vbuf + (size_t)e * 64;
        vp[j] = a0[ee];
        vp[16 + j * 3 + 0] = a1[ee] * sh0 + aw[ee][0];
        vp[16 + j * 3 + 1] = a1[ee] * sh1 + aw[ee][1];
        vp[16 + j * 3 + 2] = a1[ee] * sh2 + aw[ee][2];
    }
}

// K3: s = sqrt(exp/z) where exp>0 else 0
__global__ void k_s(const float* __restrict__ expbuf, const float* __restrict__ zbuf,
                    const int* __restrict__ edst, float* __restrict__ sbuf) {
    int e = blockIdx.x * blockDim.x + threadIdx.x;
    if (e < N_EDGES) {
        float ev = expbuf[e];
        float sres = 0.f;
        if (ev > 0.f) sres = sqrtf(ev / zbuf[edst[e]]);
        sbuf[e] = sres;
    }
}

// K4: scatter s*v directly into fp32 output
__global__ void k_scatter(const float* __restrict__ sbuf, const float* __restrict__ vbuf,
                          const int* __restrict__ edst, float* __restrict__ fout) {
    int t = blockIdx.x * blockDim.x + threadIdx.x;   // N_EDGES*64
    int e = t >> 6, col = t & 63;
    float val = sbuf[e] * vbuf[t];
    if (val != 0.f) atomicAdd(fout + edst[e] * 64 + col, val);
}

extern "C" void kernel_launch(void* const* d_in, const int* in_sizes, int n_in,
                              void* d_out, int out_size, void* d_ws, size_t ws_size,
                              hipStream_t stream) {
    const float* f_in = (const float*)d_in[0];
    const float* evec = (const float*)d_in[1];
    const int* esrc = (const int*)d_in[2];
    const int* edst = (const int*)d_in[3];
    const float* Wq0 = (const float*)d_in[4];
    const float* Wq1 = (const float*)d_in[5];
    const float* Wk1 = (const float*)d_in[6];
    const float* Wk2 = (const float*)d_in[7];
    const float* Wv1 = (const float*)d_in[8];
    const float* Wv2 = (const float*)d_in[9];
    const float* Wd0 = (const float*)d_in[10];
    const float* Wd1 = (const float*)d_in[11];

    float* ws   = (float*)d_ws;
    float* zbuf = ws + Z_OFF;
    float* w2k  = ws + W2K_OFF;
    float* w2v  = ws + W2V_OFF;
    float* qd0  = ws + QD0_OFF;
    float* qd1  = ws + QD1_OFF;
    float* expb = ws + EXP_OFF;
    float* sbuf = ws + S_OFF;
    float* vbuf = ws + V_OFF;
    float* fout = (float*)d_out;

    // zero z accumulator and the output (harness poisons both with 0xAA)
    hipMemsetAsync(zbuf, 0, (size_t)8192 * sizeof(float), stream);
    hipMemsetAsync(fout, 0, (size_t)N_NODES * 64 * sizeof(float), stream);

    k_prep_w<<<64, 256, 0, stream>>>(Wk2, Wv2, w2k, w2v);
    k_prep_node<<<512, 256, 0, stream>>>(f_in, Wq0, Wq1, Wd0, Wd1, qd0, qd1);
    k_edge<<<N_EDGES / 64, 256, 0, stream>>>(f_in, evec, esrc, edst, Wk1, Wv1,
                                             w2k, w2v, qd0, qd1, zbuf, expb, vbuf);
    k_s<<<N_EDGES / 256, 256, 0, stream>>>(expb, zbuf, edst, sbuf);
    k_scatter<<<N_EDGES * 64 / 256, 256, 0, stream>>>(sbuf, vbuf, edst, fout);
}

// Round 3
// 139.371 us; speedup vs baseline: 1.7814x; 1.7814x over previous
//
#include <hip/hip_runtime.h>
#include <hip/hip_bf16.h>

#define N_NODES 8192
#define N_EDGES 65536

// workspace layout (float offsets)
#define Z_OFF    0            // 8192
#define WF_OFF   8192         // 16384 floats = 64KB of f16 B-fragments (2 kv * 4 b * 8 t * 64 lanes * 8 f16)
#define QD0_OFF  24576        // 131072
#define QD1_OFF  155648       // 393216
#define EXP_OFF  548864       // 65536
#define S_OFF    614400       // 65536
#define V_OFF    679936       // 4194304
// total = 4874240 floats ~= 19.5 MiB

typedef _Float16 half8 __attribute__((ext_vector_type(8)));
typedef float f32x4 __attribute__((ext_vector_type(4)));

__device__ __forceinline__ float sus_f(float x) { return x > 0.f ? expf(-1.f / x) : 0.f; }
__device__ __forceinline__ float silu_f(float x) { return x / (1.f + expf(-x)); }

// K0: pack Wk2/Wv2 into MFMA B-fragment order, fp16, scale-folded.
// B[k][n] for GEMM o[e][j] = sum_k (x⊗h)[e][k] * B[k][j],  k = i*16 + h.
// Fragment layout for mfma_f32_16x16x32_f16: lane = n + 16*quad holds
// B[t*32 + quad*8 + d][n], d=0..7.  One frag-tile = 64 lanes * 8 f16 = 1KB.
// frag index g>>6 = (kv*4 + b)*8 + t.
__global__ void k_prep_w(const float* __restrict__ Wk2,
                         const float* __restrict__ Wv2,
                         half8* __restrict__ wfrag) {
    int g = blockIdx.x * blockDim.x + threadIdx.x;   // 4096 threads
    int lane = g & 63, t = (g >> 6) & 7, b = (g >> 9) & 3, kv = g >> 11;
    const float* src = kv ? Wv2 : Wk2;
    int n = lane & 15, quad = lane >> 4;
    const float SC = 0.044194173824159216f;          // 0.25 (W2/sqrt(HID)) * 1/sqrt(2*MUL)
    half8 out;
#pragma unroll
    for (int d = 0; d < 8; ++d) {
        int k = t * 32 + quad * 8 + d;
        int i = k >> 4, h = k & 15;
        out[d] = (_Float16)(src[h * 1024 + b * 256 + i * 16 + n] * SC);
    }
    wfrag[g] = out;
}

// K1: per-node qd0[j] = ad/4 * sum_i Wd0[i,j] (f0@Wq0)[i]
//     qd1[j,c] = ad/(4*sqrt3) * sum_i Wd1[i,j] (f1c@Wq1)[i]
__global__ __launch_bounds__(256) void k_prep_node(
    const float* __restrict__ f_in,
    const float* __restrict__ Wq0, const float* __restrict__ Wq1,
    const float* __restrict__ Wd0, const float* __restrict__ Wd1,
    float* __restrict__ qd0, float* __restrict__ qd1) {
    __shared__ float f0s[16][16];
    __shared__ float f1s[16][48];
    __shared__ float t0s[16][16];
    __shared__ float t1s[16][48];
    const int tid = threadIdx.x;
    const int j = tid & 15, ln = tid >> 4;
    const int n = blockIdx.x * 16 + ln;
    f0s[ln][j]         = f_in[n * 64 + j];
    f1s[ln][j * 3 + 0] = f_in[n * 64 + 16 + j * 3 + 0];
    f1s[ln][j * 3 + 1] = f_in[n * 64 + 16 + j * 3 + 1];
    f1s[ln][j * 3 + 2] = f_in[n * 64 + 16 + j * 3 + 2];
    __syncthreads();
    float t0 = 0.f, ta = 0.f, tb = 0.f, tc = 0.f;
#pragma unroll
    for (int p = 0; p < 16; ++p) {
        float wq0 = Wq0[p * 16 + j];
        float wq1 = Wq1[p * 16 + j];
        t0 += f0s[ln][p] * wq0;
        ta += f1s[ln][p * 3 + 0] * wq1;
        tb += f1s[ln][p * 3 + 1] * wq1;
        tc += f1s[ln][p * 3 + 2] * wq1;
    }
    t0s[ln][j] = t0;
    t1s[ln][j * 3 + 0] = ta; t1s[ln][j * 3 + 1] = tb; t1s[ln][j * 3 + 2] = tc;
    __syncthreads();
    float q0a = 0.f, qa = 0.f, qb = 0.f, qc = 0.f;
#pragma unroll
    for (int i = 0; i < 16; ++i) {
        float wd0 = Wd0[i * 16 + j];
        float wd1 = Wd1[i * 16 + j];
        q0a += t0s[ln][i] * wd0;
        qa  += t1s[ln][i * 3 + 0] * wd1;
        qb  += t1s[ln][i * 3 + 1] * wd1;
        qc  += t1s[ln][i * 3 + 2] * wd1;
    }
    const float S0 = 0.011048543456f;     // (1/sqrt(512))/4
    const float S1 = 0.0063788674817f;    // S0/sqrt(3)
    qd0[n * 16 + j] = q0a * S0;
    qd1[n * 48 + j * 3 + 0] = qa * S1;
    qd1[n * 48 + j * 3 + 1] = qb * S1;
    qd1[n * 48 + j * 3 + 2] = qc * S1;
}

// Build A-fragment: lane (m, quad) holds A[m][k] = x[m][i] * h[m][(quad&1)*8 + d]
// for its 8 k's; x is the per-tile scalar, h-half is in registers.
__device__ __forceinline__ half8 abuild(float x, const float (&h)[8]) {
    half8 a;
#pragma unroll
    for (int d = 0; d < 8; ++d) a[d] = (_Float16)(x * h[d]);
    return a;
}

// K2: per-edge MFMA kernel. 64 edges per 256-thread block; each wave owns 16 edges.
__global__ __launch_bounds__(256) void k_edge(
    const float* __restrict__ f_in, const float* __restrict__ evec,
    const int* __restrict__ esrc, const int* __restrict__ edst,
    const float* __restrict__ Wk1, const float* __restrict__ Wv1,
    const half8* __restrict__ wfrag,
    const float* __restrict__ qd0, const float* __restrict__ qd1,
    float* __restrict__ zbuf, float* __restrict__ expbuf, float* __restrict__ vbuf) {
    __shared__ __align__(16) float s_x0[64][17];
    __shared__ __align__(16) float s_xs[64][17];
    __shared__ __align__(16) float s_x1[3][64][17];
    __shared__ __align__(16) float s_hk[64][20];
    __shared__ __align__(16) float s_hv[64][20];
    __shared__ float s_rb[64][16];
    __shared__ float s_sh[64][4];   // sh1[0..2] = sqrt3*u, [3] = edge_cut

    const int tid = threadIdx.x;
    const int e0 = blockIdx.x * 64;

    // Phase A0: radial basis + geometry (4 threads per edge)
    {
        const int el = tid >> 2, q = tid & 3;
        const int e = e0 + el;
        float v0 = evec[e * 3 + 0];
        float v1 = evec[e * 3 + 1];
        float v2 = evec[e * 3 + 2];
        float r = sqrtf(v0 * v0 + v1 * v1 + v2 * v2);
        float rs = r * 3.4f;                       // r/step, step = 5/17
#pragma unroll
        for (int bb = 0; bb < 4; ++bb) {
            int b = q * 4 + bb;
            s_rb[el][b] = 33.734292f * sus_f(rs - (float)b) * sus_f((float)(b + 2) - rs);
        }
        if (q == 0) {
            float inv = r > 0.f ? 1.f / r : 0.f;
            const float SQ3 = 1.7320508075688772f;
            s_sh[el][0] = SQ3 * v0 * inv;
            s_sh[el][1] = SQ3 * v1 * inv;
            s_sh[el][2] = SQ3 * v2 * inv;
            s_sh[el][3] = sus_f(10.f - 2.f * r);   // edge_cut
        }
    }
    __syncthreads();

    // Phase A1: hidden layers + x staging (16 threads per edge, 4 rounds)
    {
        const int j = tid & 15, slot = tid >> 4;
#pragma unroll
        for (int s = 0; s < 4; ++s) {
            const int el = slot * 4 + s;
            const int e = e0 + el;
            float aK = 0.f, aV = 0.f;
#pragma unroll
            for (int b = 0; b < 16; ++b) {
                float rbv = s_rb[el][b];
                aK += rbv * Wk1[b * 16 + j];
                aV += rbv * Wv1[b * 16 + j];
            }
            s_hk[el][j] = silu_f(aK * 0.25f);
            s_hv[el][j] = silu_f(aV * 0.25f);
            const int src = esrc[e];
            float x0 = f_in[src * 64 + j];
            float xa = f_in[src * 64 + 16 + j * 3 + 0];
            float xb = f_in[src * 64 + 16 + j * 3 + 1];
            float xc = f_in[src * 64 + 16 + j * 3 + 2];
            s_x0[el][j] = x0;
            s_x1[0][el][j] = xa;
            s_x1[1][el][j] = xb;
            s_x1[2][el][j] = xc;
            s_xs[el][j] = (xa * s_sh[el][0] + xb * s_sh[el][1] + xc * s_sh[el][2]) * 0.57735026919f;
        }
    }
    __syncthreads();

    // Phase B: per-wave MFMA GEMMs over the wave's 16 edges.
    const int lane = tid & 63;
    const int wv = tid >> 6;
    const int m = lane & 15, quad = lane >> 4;
    const int eb = wv * 16;
    const int eloc = eb + m;               // A-operand row (edge)
    const int ihalf = quad >> 1;           // i = t*2 + ihalf
    const int hh = (quad & 1) * 8;         // h-half base

    // ---------------- K pass ----------------
    {
        float hk[8];
        *(float4*)&hk[0] = *(const float4*)&s_hk[eloc][hh];
        *(float4*)&hk[4] = *(const float4*)&s_hk[eloc][hh + 4];
        f32x4 o0 = {0.f, 0.f, 0.f, 0.f}, a1 = o0, ax = o0, ay = o0, az = o0;
#pragma unroll
        for (int t = 0; t < 8; ++t) {
            const int i = t * 2 + ihalf;
            half8 B0 = wfrag[(0 * 8 + t) * 64 + lane];
            half8 B1 = wfrag[(1 * 8 + t) * 64 + lane];
            half8 B2 = wfrag[(2 * 8 + t) * 64 + lane];
            half8 B3 = wfrag[(3 * 8 + t) * 64 + lane];
            half8 A0 = abuild(s_x0[eloc][i], hk);
            half8 As = abuild(s_xs[eloc][i], hk);
            half8 Ax = abuild(s_x1[0][eloc][i], hk);
            half8 Ay = abuild(s_x1[1][eloc][i], hk);
            half8 Az = abuild(s_x1[2][eloc][i], hk);
            o0 = __builtin_amdgcn_mfma_f32_16x16x32_f16(A0, B0, o0, 0, 0, 0);
            o0 = __builtin_amdgcn_mfma_f32_16x16x32_f16(As, B1, o0, 0, 0, 0);
            a1 = __builtin_amdgcn_mfma_f32_16x16x32_f16(A0, B2, a1, 0, 0, 0);
            ax = __builtin_amdgcn_mfma_f32_16x16x32_f16(Ax, B3, ax, 0, 0, 0);
            ay = __builtin_amdgcn_mfma_f32_16x16x32_f16(Ay, B3, ay, 0, 0, 0);
            az = __builtin_amdgcn_mfma_f32_16x16x32_f16(Az, B3, az, 0, 0, 0);
        }
        // epilogue: C layout col=lane&15=j, row=quad*4+r=edge
        const int j = m;
#pragma unroll
        for (int r = 0; r < 4; ++r) {
            const int el = eb + quad * 4 + r;
            const int e = e0 + el;
            const int dst = edst[e];
            float sh0 = s_sh[el][0], sh1 = s_sh[el][1], sh2 = s_sh[el][2];
            float k1x = a1[r] * sh0 + ax[r];
            float k1y = a1[r] * sh1 + ay[r];
            float k1z = a1[r] * sh2 + az[r];
            const float* q1p = qd1 + dst * 48 + j * 3;
            float dp = qd0[dst * 16 + j] * o0[r] + q1p[0] * k1x + q1p[1] * k1y + q1p[2] * k1z;
            dp += __shfl_xor(dp, 1);
            dp += __shfl_xor(dp, 2);
            dp += __shfl_xor(dp, 4);
            dp += __shfl_xor(dp, 8);
            if (j == 0) {
                float ev = s_sh[el][3] * expf(dp);
                expbuf[e] = ev;
                atomicAdd(zbuf + dst, ev);
            }
        }
    }

    // ---------------- V pass ----------------
    {
        float hv[8];
        *(float4*)&hv[0] = *(const float4*)&s_hv[eloc][hh];
        *(float4*)&hv[4] = *(const float4*)&s_hv[eloc][hh + 4];
        f32x4 o0 = {0.f, 0.f, 0.f, 0.f}, a1 = o0, ax = o0, ay = o0, az = o0;
        const half8* wfv = wfrag + 32 * 64;
#pragma unroll
        for (int t = 0; t < 8; ++t) {
            const int i = t * 2 + ihalf;
            half8 B0 = wfv[(0 * 8 + t) * 64 + lane];
            half8 B1 = wfv[(1 * 8 + t) * 64 + lane];
            half8 B2 = wfv[(2 * 8 + t) * 64 + lane];
            half8 B3 = wfv[(3 * 8 + t) * 64 + lane];
            half8 A0 = abuild(s_x0[eloc][i], hv);
            half8 As = abuild(s_xs[eloc][i], hv);
            half8 Ax = abuild(s_x1[0][eloc][i], hv);
            half8 Ay = abuild(s_x1[1][eloc][i], hv);
            half8 Az = abuild(s_x1[2][eloc][i], hv);
            o0 = __builtin_amdgcn_mfma_f32_16x16x32_f16(A0, B0, o0, 0, 0, 0);
            o0 = __builtin_amdgcn_mfma_f32_16x16x32_f16(As, B1, o0, 0, 0, 0);
            a1 = __builtin_amdgcn_mfma_f32_16x16x32_f16(A0, B2, a1, 0, 0, 0);
            ax = __builtin_amdgcn_mfma_f32_16x16x32_f16(Ax, B3, ax, 0, 0, 0);
            ay = __builtin_amdgcn_mfma_f32_16x16x32_f16(Ay, B3, ay, 0, 0, 0);
            az = __builtin_amdgcn_mfma_f32_16x16x32_f16(Az, B3, az, 0, 0, 0);
        }
        const int j = m;
#pragma unroll
        for (int r = 0; r < 4; ++r) {
            const int el = eb + quad * 4 + r;
            const int e = e0 + el;
            float sh0 = s_sh[el][0], sh1 = s_sh[el][1], sh2 = s_sh[el][2];
            float* vp = vbuf + (size_t)e * 64;
            vp[j] = o0[r];
            vp[16 + j * 3 + 0] = a1[r] * sh0 + ax[r];
            vp[16 + j * 3 + 1] = a1[r] * sh1 + ay[r];
            vp[16 + j * 3 + 2] = a1[r] * sh2 + az[r];
        }
    }
}

// K3: s = sqrt(exp/z) where exp>0 else 0
__global__ void k_s(const float* __restrict__ expbuf, const float* __restrict__ zbuf,
                    const int* __restrict__ edst, float* __restrict__ sbuf) {
    int e = blockIdx.x * blockDim.x + threadIdx.x;
    if (e < N_EDGES) {
        float ev = expbuf[e];
        float sres = 0.f;
        if (ev > 0.f) sres = sqrtf(ev / zbuf[edst[e]]);
        sbuf[e] = sres;
    }
}

// K4: scatter s*v directly into fp32 output
__global__ void k_scatter(const float* __restrict__ sbuf, const float* __restrict__ vbuf,
                          const int* __restrict__ edst, float* __restrict__ fout) {
    int t = blockIdx.x * blockDim.x + threadIdx.x;   // N_EDGES*64
    int e = t >> 6, col = t & 63;
    float val = sbuf[e] * vbuf[t];
    if (val != 0.f) atomicAdd(fout + edst[e] * 64 + col, val);
}

extern "C" void kernel_launch(void* const* d_in, const int* in_sizes, int n_in,
                              void* d_out, int out_size, void* d_ws, size_t ws_size,
                              hipStream_t stream) {
    const float* f_in = (const float*)d_in[0];
    const float* evec = (const float*)d_in[1];
    const int* esrc = (const int*)d_in[2];
    const int* edst = (const int*)d_in[3];
    const float* Wq0 = (const float*)d_in[4];
    const float* Wq1 = (const float*)d_in[5];
    const float* Wk1 = (const float*)d_in[6];
    const float* Wk2 = (const float*)d_in[7];
    const float* Wv1 = (const float*)d_in[8];
    const float* Wv2 = (const float*)d_in[9];
    const float* Wd0 = (const float*)d_in[10];
    const float* Wd1 = (const float*)d_in[11];

    float* ws   = (float*)d_ws;
    float* zbuf = ws + Z_OFF;
    half8* wfrag = (half8*)(ws + WF_OFF);
    float* qd0  = ws + QD0_OFF;
    float* qd1  = ws + QD1_OFF;
    float* expb = ws + EXP_OFF;
    float* sbuf = ws + S_OFF;
    float* vbuf = ws + V_OFF;
    float* fout = (float*)d_out;

    hipMemsetAsync(zbuf, 0, (size_t)8192 * sizeof(float), stream);
    hipMemsetAsync(fout, 0, (size_t)N_NODES * 64 * sizeof(float), stream);

    k_prep_w<<<16, 256, 0, stream>>>(Wk2, Wv2, wfrag);
    k_prep_node<<<512, 256, 0, stream>>>(f_in, Wq0, Wq1, Wd0, Wd1, qd0, qd1);
    k_edge<<<N_EDGES / 64, 256, 0, stream>>>(f_in, evec, esrc, edst, Wk1, Wv1,
                                             wfrag, qd0, qd1, zbuf, expb, vbuf);
    k_s<<<N_EDGES / 256, 256, 0, stream>>>(expb, zbuf, edst, sbuf);
    k_scatter<<<N_EDGES * 64 / 256, 256, 0, stream>>>(sbuf, vbuf, edst, fout);
}

// Round 4
// 130.360 us; speedup vs baseline: 1.9046x; 1.0691x over previous
//
#include <hip/hip_runtime.h>
#include <hip/hip_bf16.h>

#define N_NODES 8192
#define N_EDGES 65536

// workspace layout (float offsets)
#define Z_OFF    0            // 8192 floats
#define CNT_OFF  8192         // 8192 ints (degree counters, then CSR cursors)
#define RP_OFF   16384        // 8193 ints (CSR rowptr), reserve 8448
#define WF_OFF   24832        // 16384 floats = 64KB f16 B-fragments
#define QD0_OFF  41216        // 131072
#define QD1_OFF  172288       // 393216 (3 planes of [8192][16])
#define EXP_OFF  565504       // 65536
#define EIDX_OFF 631040       // 65536 ints (CSR edge ids)
#define V_OFF    696576       // 4194304
// total ~4.89M floats ~= 19.6 MiB

typedef _Float16 half8 __attribute__((ext_vector_type(8)));
typedef float f32x4 __attribute__((ext_vector_type(4)));

__device__ __forceinline__ float sus_f(float x) { return x > 0.f ? expf(-1.f / x) : 0.f; }
__device__ __forceinline__ float silu_f(float x) { return x / (1.f + expf(-x)); }

__device__ __forceinline__ half8 vmul(half8 v, _Float16 s) {
    half8 r;
#pragma unroll
    for (int d = 0; d < 8; ++d) r[d] = v[d] * s;
    return r;
}

// Fused prep: blocks [0,16) pack W-fragments; [16,528) per-node q·Wd; [528,592) degree count.
// B-fragment order (k = h*16 + i so A-build is h-scalar × x-vector):
// lane = n + 16*quad holds B[t*32 + quad*8 + d][n], d=0..7; frag idx = (kv*4+b)*8 + t.
__global__ __launch_bounds__(256) void k_prep(
    const float* __restrict__ f_in,
    const float* __restrict__ Wq0, const float* __restrict__ Wq1,
    const float* __restrict__ Wd0, const float* __restrict__ Wd1,
    const float* __restrict__ Wk2, const float* __restrict__ Wv2,
    const int* __restrict__ edst,
    half8* __restrict__ wfrag, float* __restrict__ qd0, float* __restrict__ qd1,
    int* __restrict__ cnt) {
    __shared__ float f0s[16][16];
    __shared__ float f1s[16][48];
    __shared__ float t0s[16][16];
    __shared__ float t1s[16][48];
    const int blk = blockIdx.x;
    const int tid = threadIdx.x;

    if (blk < 16) {                       // ---- W-fragment pack ----
        int g = blk * 256 + tid;          // 4096 frags-of-8
        int lane = g & 63, t = (g >> 6) & 7, b = (g >> 9) & 3, kv = g >> 11;
        const float* src = kv ? Wv2 : Wk2;
        int n = lane & 15, quad = lane >> 4;
        const float SC = 0.044194173824159216f;   // 0.25 (W2/sqrt16) * 1/sqrt(2*MUL)
        half8 out;
#pragma unroll
        for (int d = 0; d < 8; ++d) {
            int k = t * 32 + quad * 8 + d;
            int i = k & 15, h = k >> 4;
            out[d] = (_Float16)(src[h * 1024 + b * 256 + i * 16 + n] * SC);
        }
        wfrag[g] = out;
        return;
    }
    if (blk >= 528) {                     // ---- degree count ----
        int base = (blk - 528) * 256 + tid;
#pragma unroll
        for (int k = 0; k < 4; ++k) atomicAdd(cnt + edst[base + k * 16384], 1);
        return;
    }
    // ---- per-node qd precompute ----
    const int j = tid & 15, ln = tid >> 4;
    const int n = (blk - 16) * 16 + ln;
    f0s[ln][j]         = f_in[n * 64 + j];
    f1s[ln][j * 3 + 0] = f_in[n * 64 + 16 + j * 3 + 0];
    f1s[ln][j * 3 + 1] = f_in[n * 64 + 16 + j * 3 + 1];
    f1s[ln][j * 3 + 2] = f_in[n * 64 + 16 + j * 3 + 2];
    __syncthreads();
    float t0 = 0.f, ta = 0.f, tb = 0.f, tc = 0.f;
#pragma unroll
    for (int p = 0; p < 16; ++p) {
        float wq0 = Wq0[p * 16 + j];
        float wq1 = Wq1[p * 16 + j];
        t0 += f0s[ln][p] * wq0;
        ta += f1s[ln][p * 3 + 0] * wq1;
        tb += f1s[ln][p * 3 + 1] * wq1;
        tc += f1s[ln][p * 3 + 2] * wq1;
    }
    t0s[ln][j] = t0;
    t1s[ln][j * 3 + 0] = ta; t1s[ln][j * 3 + 1] = tb; t1s[ln][j * 3 + 2] = tc;
    __syncthreads();
    float q0a = 0.f, qa = 0.f, qb = 0.f, qc = 0.f;
#pragma unroll
    for (int i = 0; i < 16; ++i) {
        float wd0 = Wd0[i * 16 + j];
        float wd1 = Wd1[i * 16 + j];
        q0a += t0s[ln][i] * wd0;
        qa  += t1s[ln][i * 3 + 0] * wd1;
        qb  += t1s[ln][i * 3 + 1] * wd1;
        qc  += t1s[ln][i * 3 + 2] * wd1;
    }
    const float S0 = 0.011048543456f;     // (1/sqrt(512))/4
    const float S1 = 0.0063788674817f;    // S0/sqrt(3)
    qd0[n * 16 + j] = q0a * S0;
    qd1[0 * 131072 + n * 16 + j] = qa * S1;
    qd1[1 * 131072 + n * 16 + j] = qb * S1;
    qd1[2 * 131072 + n * 16 + j] = qc * S1;
}

// CSR scan: 1 block, 1024 threads, 8 nodes each. rowptr = exclusive prefix; cnt reset to base.
__global__ __launch_bounds__(1024) void k_scan(int* __restrict__ cnt, int* __restrict__ rowptr) {
    __shared__ int part[1024];
    const int t = threadIdx.x;
    const int base = t * 8;
    int v[8]; int s = 0;
#pragma unroll
    for (int i = 0; i < 8; ++i) { v[i] = cnt[base + i]; s += v[i]; }
    part[t] = s;
    __syncthreads();
    for (int off = 1; off < 1024; off <<= 1) {
        int x = (t >= off) ? part[t - off] : 0;
        __syncthreads();
        part[t] += x;
        __syncthreads();
    }
    int run = part[t] - s;
#pragma unroll
    for (int i = 0; i < 8; ++i) { rowptr[base + i] = run; cnt[base + i] = run; run += v[i]; }
    if (t == 1023) rowptr[8192] = run;
}

__global__ void k_scidx(const int* __restrict__ edst, int* __restrict__ cnt,
                        int* __restrict__ eidx) {
    int e = blockIdx.x * blockDim.x + threadIdx.x;
    int slot = atomicAdd(cnt + edst[e], 1);
    eidx[slot] = e;
}

// K2: per-edge MFMA kernel. 64 edges/block; each wave owns 16 edges.
__global__ __launch_bounds__(256) void k_edge(
    const float* __restrict__ f_in, const float* __restrict__ evec,
    const int* __restrict__ esrc, const int* __restrict__ edst,
    const float* __restrict__ Wk1, const float* __restrict__ Wv1,
    const half8* __restrict__ wfrag,
    const float* __restrict__ qd0, const float* __restrict__ qd1,
    float* __restrict__ zbuf, float* __restrict__ expbuf, float* __restrict__ vbuf) {
    __shared__ __align__(16) _Float16 s_x0h[64][24];
    __shared__ __align__(16) _Float16 s_xsh[64][24];
    __shared__ __align__(16) _Float16 s_x1h[3][64][24];
    __shared__ __align__(16) _Float16 s_hkh[64][16];   // [el][(h&1)*8 + (h>>1)]
    __shared__ __align__(16) _Float16 s_hvh[64][16];
    __shared__ float s_rb[64][16];
    __shared__ float s_sh[64][4];   // sqrt3*u, edge_cut

    const int tid = threadIdx.x;
    const int e0 = blockIdx.x * 64;

    // Phase A0: radial basis + geometry (4 threads/edge)
    {
        const int el = tid >> 2, q = tid & 3;
        const int e = e0 + el;
        float v0 = evec[e * 3 + 0];
        float v1 = evec[e * 3 + 1];
        float v2 = evec[e * 3 + 2];
        float r = sqrtf(v0 * v0 + v1 * v1 + v2 * v2);
        float rs = r * 3.4f;
#pragma unroll
        for (int bb = 0; bb < 4; ++bb) {
            int b = q * 4 + bb;
            s_rb[el][b] = 33.734292f * sus_f(rs - (float)b) * sus_f((float)(b + 2) - rs);
        }
        if (q == 0) {
            float inv = r > 0.f ? 1.f / r : 0.f;
            const float SQ3 = 1.7320508075688772f;
            s_sh[el][0] = SQ3 * v0 * inv;
            s_sh[el][1] = SQ3 * v1 * inv;
            s_sh[el][2] = SQ3 * v2 * inv;
            s_sh[el][3] = sus_f(10.f - 2.f * r);
        }
    }
    __syncthreads();

    // Phase A1: radial MLP hidden + x staging as fp16 (16 threads/edge, 4 rounds)
    {
        const int j = tid & 15, slot = tid >> 4;
#pragma unroll
        for (int s = 0; s < 4; ++s) {
            const int el = slot * 4 + s;
            const int e = e0 + el;
            float aK = 0.f, aV = 0.f;
#pragma unroll
            for (int b = 0; b < 16; ++b) {
                float rbv = s_rb[el][b];
                aK += rbv * Wk1[b * 16 + j];
                aV += rbv * Wv1[b * 16 + j];
            }
            s_hkh[el][(j & 1) * 8 + (j >> 1)] = (_Float16)silu_f(aK * 0.25f);
            s_hvh[el][(j & 1) * 8 + (j >> 1)] = (_Float16)silu_f(aV * 0.25f);
            const int src = esrc[e];
            float x0 = f_in[src * 64 + j];
            float xa = f_in[src * 64 + 16 + j * 3 + 0];
            float xb = f_in[src * 64 + 16 + j * 3 + 1];
            float xc = f_in[src * 64 + 16 + j * 3 + 2];
            s_x0h[el][j] = (_Float16)x0;
            s_x1h[0][el][j] = (_Float16)xa;
            s_x1h[1][el][j] = (_Float16)xb;
            s_x1h[2][el][j] = (_Float16)xc;
            s_xsh[el][j] = (_Float16)((xa * s_sh[el][0] + xb * s_sh[el][1] + xc * s_sh[el][2])
                                      * 0.57735026919f);
        }
    }
    __syncthreads();

    // Phase B: per-wave MFMA GEMMs. Lane(m,quad): A[m][k] = x[m][k&15] * h[m][k>>4],
    // k = t*32 + quad*8 + d  ->  x-range fixed = hh+[0,8), h scalar = t*2+ihalf.
    const int lane = tid & 63;
    const int wv = tid >> 6;
    const int m = lane & 15, quad = lane >> 4;
    const int eb = wv * 16;
    const int eloc = eb + m;
    const int ihalf = quad >> 1;
    const int hh = (quad & 1) * 8;

    half8 X0 = *(const half8*)&s_x0h[eloc][hh];
    half8 XS = *(const half8*)&s_xsh[eloc][hh];
    half8 Xa = *(const half8*)&s_x1h[0][eloc][hh];
    half8 Xb = *(const half8*)&s_x1h[1][eloc][hh];
    half8 Xc = *(const half8*)&s_x1h[2][eloc][hh];
    half8 HK = *(const half8*)&s_hkh[eloc][ihalf * 8];
    half8 HV = *(const half8*)&s_hvh[eloc][ihalf * 8];

    // ---------------- K pass ----------------
    {
        f32x4 o0 = {0.f, 0.f, 0.f, 0.f}, a1 = o0, ax = o0, ay = o0, az = o0;
#pragma unroll
        for (int t = 0; t < 8; ++t) {
            _Float16 hs = HK[t];
            half8 B0 = wfrag[(0 * 8 + t) * 64 + lane];
            half8 B1 = wfrag[(1 * 8 + t) * 64 + lane];
            half8 B2 = wfrag[(2 * 8 + t) * 64 + lane];
            half8 B3 = wfrag[(3 * 8 + t) * 64 + lane];
            half8 A0 = vmul(X0, hs);
            half8 As = vmul(XS, hs);
            half8 Aa = vmul(Xa, hs);
            half8 Ab = vmul(Xb, hs);
            half8 Ac = vmul(Xc, hs);
            o0 = __builtin_amdgcn_mfma_f32_16x16x32_f16(A0, B0, o0, 0, 0, 0);
            o0 = __builtin_amdgcn_mfma_f32_16x16x32_f16(As, B1, o0, 0, 0, 0);
            a1 = __builtin_amdgcn_mfma_f32_16x16x32_f16(A0, B2, a1, 0, 0, 0);
            ax = __builtin_amdgcn_mfma_f32_16x16x32_f16(Aa, B3, ax, 0, 0, 0);
            ay = __builtin_amdgcn_mfma_f32_16x16x32_f16(Ab, B3, ay, 0, 0, 0);
            az = __builtin_amdgcn_mfma_f32_16x16x32_f16(Ac, B3, az, 0, 0, 0);
        }
        const int j = m;
#pragma unroll
        for (int r = 0; r < 4; ++r) {
            const int el = eb + quad * 4 + r;
            const int e = e0 + el;
            const int dst = edst[e];
            float sh0 = s_sh[el][0], sh1 = s_sh[el][1], sh2 = s_sh[el][2];
            float k1x = a1[r] * sh0 + ax[r];
            float k1y = a1[r] * sh1 + ay[r];
            float k1z = a1[r] * sh2 + az[r];
            float dp = qd0[dst * 16 + j] * o0[r]
                     + qd1[0 * 131072 + dst * 16 + j] * k1x
                     + qd1[1 * 131072 + dst * 16 + j] * k1y
                     + qd1[2 * 131072 + dst * 16 + j] * k1z;
            dp += __shfl_xor(dp, 1);
            dp += __shfl_xor(dp, 2);
            dp += __shfl_xor(dp, 4);
            dp += __shfl_xor(dp, 8);
            if (j == 0) {
                float ev = s_sh[el][3] * expf(dp);
                expbuf[e] = ev;
                atomicAdd(zbuf + dst, ev);
            }
        }
    }

    // ---------------- V pass ----------------
    {
        f32x4 o0 = {0.f, 0.f, 0.f, 0.f}, a1 = o0, ax = o0, ay = o0, az = o0;
        const half8* wfv = wfrag + 32 * 64;
#pragma unroll
        for (int t = 0; t < 8; ++t) {
            _Float16 hs = HV[t];
            half8 B0 = wfv[(0 * 8 + t) * 64 + lane];
            half8 B1 = wfv[(1 * 8 + t) * 64 + lane];
            half8 B2 = wfv[(2 * 8 + t) * 64 + lane];
            half8 B3 = wfv[(3 * 8 + t) * 64 + lane];
            half8 A0 = vmul(X0, hs);
            half8 As = vmul(XS, hs);
            half8 Aa = vmul(Xa, hs);
            half8 Ab = vmul(Xb, hs);
            half8 Ac = vmul(Xc, hs);
            o0 = __builtin_amdgcn_mfma_f32_16x16x32_f16(A0, B0, o0, 0, 0, 0);
            o0 = __builtin_amdgcn_mfma_f32_16x16x32_f16(As, B1, o0, 0, 0, 0);
            a1 = __builtin_amdgcn_mfma_f32_16x16x32_f16(A0, B2, a1, 0, 0, 0);
            ax = __builtin_amdgcn_mfma_f32_16x16x32_f16(Aa, B3, ax, 0, 0, 0);
            ay = __builtin_amdgcn_mfma_f32_16x16x32_f16(Ab, B3, ay, 0, 0, 0);
            az = __builtin_amdgcn_mfma_f32_16x16x32_f16(Ac, B3, az, 0, 0, 0);
        }
        const int j = m;
#pragma unroll
        for (int r = 0; r < 4; ++r) {
            const int el = eb + quad * 4 + r;
            const int e = e0 + el;
            float sh0 = s_sh[el][0], sh1 = s_sh[el][1], sh2 = s_sh[el][2];
            float* vp = vbuf + (size_t)e * 64;
            vp[j] = o0[r];
            vp[16 + j * 3 + 0] = a1[r] * sh0 + ax[r];
            vp[16 + j * 3 + 1] = a1[r] * sh1 + ay[r];
            vp[16 + j * 3 + 2] = a1[r] * sh2 + az[r];
        }
    }
}

// k_out: per-node gather. 4 nodes/block, 64 threads/node.
__global__ __launch_bounds__(256) void k_out(
    const int* __restrict__ rowptr, const int* __restrict__ eidx,
    const float* __restrict__ expbuf, const float* __restrict__ zbuf,
    const float* __restrict__ vbuf, float* __restrict__ fout) {
    const int col = threadIdx.x & 63;
    const int n = blockIdx.x * 4 + (threadIdx.x >> 6);
    const int s0 = rowptr[n], s1 = rowptr[n + 1];
    float z = zbuf[n];
    float zinv = z > 0.f ? 1.f / z : 0.f;
    float acc = 0.f;
    for (int p = s0; p < s1; ++p) {
        int e = eidx[p];
        float ev = expbuf[e];
        float s = ev > 0.f ? sqrtf(ev * zinv) : 0.f;
        acc += s * vbuf[(size_t)e * 64 + col];
    }
    fout[n * 64 + col] = acc;
}

extern "C" void kernel_launch(void* const* d_in, const int* in_sizes, int n_in,
                              void* d_out, int out_size, void* d_ws, size_t ws_size,
                              hipStream_t stream) {
    const float* f_in = (const float*)d_in[0];
    const float* evec = (const float*)d_in[1];
    const int* esrc = (const int*)d_in[2];
    const int* edst = (const int*)d_in[3];
    const float* Wq0 = (const float*)d_in[4];
    const float* Wq1 = (const float*)d_in[5];
    const float* Wk1 = (const float*)d_in[6];
    const float* Wk2 = (const float*)d_in[7];
    const float* Wv1 = (const float*)d_in[8];
    const float* Wv2 = (const float*)d_in[9];
    const float* Wd0 = (const float*)d_in[10];
    const float* Wd1 = (const float*)d_in[11];

    float* ws    = (float*)d_ws;
    float* zbuf  = ws + Z_OFF;
    int*   cnt   = (int*)(ws + CNT_OFF);
    int*   rowptr= (int*)(ws + RP_OFF);
    half8* wfrag = (half8*)(ws + WF_OFF);
    float* qd0   = ws + QD0_OFF;
    float* qd1   = ws + QD1_OFF;
    float* expb  = ws + EXP_OFF;
    int*   eidx  = (int*)(ws + EIDX_OFF);
    float* vbuf  = ws + V_OFF;
    float* fout  = (float*)d_out;

    // zero zbuf + cnt (contiguous)
    hipMemsetAsync(ws, 0, (size_t)16384 * sizeof(float), stream);

    k_prep<<<592, 256, 0, stream>>>(f_in, Wq0, Wq1, Wd0, Wd1, Wk2, Wv2, edst,
                                    wfrag, qd0, qd1, cnt);
    k_scan<<<1, 1024, 0, stream>>>(cnt, rowptr);
    k_scidx<<<N_EDGES / 256, 256, 0, stream>>>(edst, cnt, eidx);
    k_edge<<<N_EDGES / 64, 256, 0, stream>>>(f_in, evec, esrc, edst, Wk1, Wv1,
                                             wfrag, qd0, qd1, zbuf, expb, vbuf);
    k_out<<<N_NODES / 4, 256, 0, stream>>>(rowptr, eidx, expb, zbuf, vbuf, fout);
}

// Round 5
// 127.085 us; speedup vs baseline: 1.9536x; 1.0258x over previous
//
#include <hip/hip_runtime.h>
#include <hip/hip_bf16.h>

#define N_NODES 8192
#define N_EDGES 65536

// workspace layout (float offsets)
#define CNT_OFF  0            // 8192 ints (degree counters -> CSR cursors)
#define RP_OFF   8192         // 8193 ints rowptr (reserve 8448)
#define WF_OFF   16640        // 16384 floats = 64KB f16 B-fragments
#define QD0_OFF  33024        // 131072
#define QD1_OFF  164096       // 393216 (3 planes of [8192][16])
#define EXP_OFF  557312       // 65536 floats, slot-ordered
#define VH_OFF   622848       // 4194304 halfs = 2097152 floats, slot-ordered
// total ~2.72M floats ~= 10.9 MiB

typedef _Float16 half8 __attribute__((ext_vector_type(8)));
typedef float f32x4 __attribute__((ext_vector_type(4)));

__device__ __forceinline__ float sus_f(float x) { return x > 0.f ? expf(-1.f / x) : 0.f; }
__device__ __forceinline__ float silu_f(float x) { return x / (1.f + expf(-x)); }

__device__ __forceinline__ half8 vmul(half8 v, _Float16 s) {
    half8 r;
#pragma unroll
    for (int d = 0; d < 8; ++d) r[d] = v[d] * s;
    return r;
}

// Fused prep: blocks [0,16) pack W-fragments; [16,528) per-node q·Wd; [528,592) degree count.
__global__ __launch_bounds__(256) void k_prep(
    const float* __restrict__ f_in,
    const float* __restrict__ Wq0, const float* __restrict__ Wq1,
    const float* __restrict__ Wd0, const float* __restrict__ Wd1,
    const float* __restrict__ Wk2, const float* __restrict__ Wv2,
    const int* __restrict__ edst,
    half8* __restrict__ wfrag, float* __restrict__ qd0, float* __restrict__ qd1,
    int* __restrict__ cnt) {
    __shared__ float f0s[16][16];
    __shared__ float f1s[16][48];
    __shared__ float t0s[16][16];
    __shared__ float t1s[16][48];
    const int blk = blockIdx.x;
    const int tid = threadIdx.x;

    if (blk < 16) {                       // ---- W-fragment pack (k = h*16 + i) ----
        int g = blk * 256 + tid;          // 4096 frags-of-8
        int lane = g & 63, t = (g >> 6) & 7, b = (g >> 9) & 3, kv = g >> 11;
        const float* src = kv ? Wv2 : Wk2;
        int n = lane & 15, quad = lane >> 4;
        const float SC = 0.044194173824159216f;   // 0.25 (W2/sqrt16) * 1/sqrt(2*MUL)
        half8 out;
#pragma unroll
        for (int d = 0; d < 8; ++d) {
            int k = t * 32 + quad * 8 + d;
            int i = k & 15, h = k >> 4;
            out[d] = (_Float16)(src[h * 1024 + b * 256 + i * 16 + n] * SC);
        }
        wfrag[g] = out;
        return;
    }
    if (blk >= 528) {                     // ---- degree count ----
        int base = (blk - 528) * 256 + tid;
#pragma unroll
        for (int k = 0; k < 4; ++k) atomicAdd(cnt + edst[base + k * 16384], 1);
        return;
    }
    // ---- per-node qd precompute ----
    const int j = tid & 15, ln = tid >> 4;
    const int n = (blk - 16) * 16 + ln;
    f0s[ln][j]         = f_in[n * 64 + j];
    f1s[ln][j * 3 + 0] = f_in[n * 64 + 16 + j * 3 + 0];
    f1s[ln][j * 3 + 1] = f_in[n * 64 + 16 + j * 3 + 1];
    f1s[ln][j * 3 + 2] = f_in[n * 64 + 16 + j * 3 + 2];
    __syncthreads();
    float t0 = 0.f, ta = 0.f, tb = 0.f, tc = 0.f;
#pragma unroll
    for (int p = 0; p < 16; ++p) {
        float wq0 = Wq0[p * 16 + j];
        float wq1 = Wq1[p * 16 + j];
        t0 += f0s[ln][p] * wq0;
        ta += f1s[ln][p * 3 + 0] * wq1;
        tb += f1s[ln][p * 3 + 1] * wq1;
        tc += f1s[ln][p * 3 + 2] * wq1;
    }
    t0s[ln][j] = t0;
    t1s[ln][j * 3 + 0] = ta; t1s[ln][j * 3 + 1] = tb; t1s[ln][j * 3 + 2] = tc;
    __syncthreads();
    float q0a = 0.f, qa = 0.f, qb = 0.f, qc = 0.f;
#pragma unroll
    for (int i = 0; i < 16; ++i) {
        float wd0 = Wd0[i * 16 + j];
        float wd1 = Wd1[i * 16 + j];
        q0a += t0s[ln][i] * wd0;
        qa  += t1s[ln][i * 3 + 0] * wd1;
        qb  += t1s[ln][i * 3 + 1] * wd1;
        qc  += t1s[ln][i * 3 + 2] * wd1;
    }
    const float S0 = 0.011048543456f;     // (1/sqrt(512))/4
    const float S1 = 0.0063788674817f;    // S0/sqrt(3)
    qd0[n * 16 + j] = q0a * S0;
    qd1[0 * 131072 + n * 16 + j] = qa * S1;
    qd1[1 * 131072 + n * 16 + j] = qb * S1;
    qd1[2 * 131072 + n * 16 + j] = qc * S1;
}

// CSR scan: 1 block, 1024 threads, 8 nodes each. shfl wave-scan, 2 barriers.
// rowptr = exclusive prefix; cnt reset to base (cursor init).
__global__ __launch_bounds__(1024) void k_scan(int* __restrict__ cnt, int* __restrict__ rowptr) {
    __shared__ int wsum[16];
    __shared__ int woff[16];
    const int t = threadIdx.x;
    const int lane = t & 63, wv = t >> 6;
    const int base = t * 8;
    int v[8]; int s = 0;
    int4 p0 = ((const int4*)cnt)[t * 2];
    int4 p1 = ((const int4*)cnt)[t * 2 + 1];
    v[0] = p0.x; v[1] = p0.y; v[2] = p0.z; v[3] = p0.w;
    v[4] = p1.x; v[5] = p1.y; v[6] = p1.z; v[7] = p1.w;
#pragma unroll
    for (int i = 0; i < 8; ++i) s += v[i];
    int own = s;
    // inclusive wave scan
#pragma unroll
    for (int off = 1; off < 64; off <<= 1) {
        int u = __shfl_up(s, off);
        if (lane >= off) s += u;
    }
    if (lane == 63) wsum[wv] = s;
    __syncthreads();
    if (wv == 0 && lane < 16) {
        int u = wsum[lane];
        int sc = u;
#pragma unroll
        for (int off = 1; off < 16; off <<= 1) {
            int x = __shfl_up(sc, off);
            if (lane >= off) sc += x;
        }
        woff[lane] = sc - u;   // exclusive wave offset
    }
    __syncthreads();
    int run = woff[wv] + (s - own);
#pragma unroll
    for (int i = 0; i < 8; ++i) { rowptr[base + i] = run; cnt[base + i] = run; run += v[i]; }
    if (t == 1023) rowptr[8192] = run;
}

// K2: per-edge MFMA kernel. 64 edges/block; each wave owns 16 edges.
// Assigns CSR slot per edge, writes exp + fp16 v slot-ordered (coalesced via LDS tile).
__global__ __launch_bounds__(256) void k_edge(
    const float* __restrict__ f_in, const float* __restrict__ evec,
    const int* __restrict__ esrc, const int* __restrict__ edst,
    const float* __restrict__ Wk1, const float* __restrict__ Wv1,
    const half8* __restrict__ wfrag,
    const float* __restrict__ qd0, const float* __restrict__ qd1,
    int* __restrict__ cursor, float* __restrict__ expbuf, _Float16* __restrict__ vh) {
    __shared__ __align__(16) _Float16 s_x0h[64][24];
    __shared__ __align__(16) _Float16 s_xsh[64][24];
    __shared__ __align__(16) _Float16 s_x1h[3][64][24];
    __shared__ __align__(16) _Float16 s_hkh[64][16];   // [el][(h&1)*8 + (h>>1)]
    __shared__ __align__(16) _Float16 s_hvh[64][16];
    __shared__ __align__(16) _Float16 s_vt[64][72];    // v-tile, fp16
    __shared__ float s_rb[64][16];
    __shared__ float s_sh[64][4];   // sqrt3*u, edge_cut
    __shared__ int   s_slot[64];

    const int tid = threadIdx.x;
    const int e0 = blockIdx.x * 64;

    // Phase A0: radial basis + geometry (4 threads/edge)
    {
        const int el = tid >> 2, q = tid & 3;
        const int e = e0 + el;
        float v0 = evec[e * 3 + 0];
        float v1 = evec[e * 3 + 1];
        float v2 = evec[e * 3 + 2];
        float r = sqrtf(v0 * v0 + v1 * v1 + v2 * v2);
        float rs = r * 3.4f;
#pragma unroll
        for (int bb = 0; bb < 4; ++bb) {
            int b = q * 4 + bb;
            s_rb[el][b] = 33.734292f * sus_f(rs - (float)b) * sus_f((float)(b + 2) - rs);
        }
        if (q == 0) {
            float inv = r > 0.f ? 1.f / r : 0.f;
            const float SQ3 = 1.7320508075688772f;
            s_sh[el][0] = SQ3 * v0 * inv;
            s_sh[el][1] = SQ3 * v1 * inv;
            s_sh[el][2] = SQ3 * v2 * inv;
            s_sh[el][3] = sus_f(10.f - 2.f * r);
        }
    }
    __syncthreads();

    // Phase A1: radial MLP hidden + x staging as fp16 (16 threads/edge, 4 rounds)
    {
        const int j = tid & 15, slot = tid >> 4;
#pragma unroll
        for (int s = 0; s < 4; ++s) {
            const int el = slot * 4 + s;
            const int e = e0 + el;
            float aK = 0.f, aV = 0.f;
#pragma unroll
            for (int b = 0; b < 16; ++b) {
                float rbv = s_rb[el][b];
                aK += rbv * Wk1[b * 16 + j];
                aV += rbv * Wv1[b * 16 + j];
            }
            s_hkh[el][(j & 1) * 8 + (j >> 1)] = (_Float16)silu_f(aK * 0.25f);
            s_hvh[el][(j & 1) * 8 + (j >> 1)] = (_Float16)silu_f(aV * 0.25f);
            const int src = esrc[e];
            float x0 = f_in[src * 64 + j];
            float xa = f_in[src * 64 + 16 + j * 3 + 0];
            float xb = f_in[src * 64 + 16 + j * 3 + 1];
            float xc = f_in[src * 64 + 16 + j * 3 + 2];
            s_x0h[el][j] = (_Float16)x0;
            s_x1h[0][el][j] = (_Float16)xa;
            s_x1h[1][el][j] = (_Float16)xb;
            s_x1h[2][el][j] = (_Float16)xc;
            s_xsh[el][j] = (_Float16)((xa * s_sh[el][0] + xb * s_sh[el][1] + xc * s_sh[el][2])
                                      * 0.57735026919f);
        }
    }
    __syncthreads();

    // Phase B: per-wave MFMA GEMMs. Lane(m,quad): A[m][k] = x[m][k&15] * h[m][k>>4].
    const int lane = tid & 63;
    const int wv = tid >> 6;
    const int m = lane & 15, quad = lane >> 4;
    const int eb = wv * 16;
    const int eloc = eb + m;
    const int ihalf = quad >> 1;
    const int hh = (quad & 1) * 8;

    half8 X0 = *(const half8*)&s_x0h[eloc][hh];
    half8 XS = *(const half8*)&s_xsh[eloc][hh];
    half8 Xa = *(const half8*)&s_x1h[0][eloc][hh];
    half8 Xb = *(const half8*)&s_x1h[1][eloc][hh];
    half8 Xc = *(const half8*)&s_x1h[2][eloc][hh];
    half8 HK = *(const half8*)&s_hkh[eloc][ihalf * 8];
    half8 HV = *(const half8*)&s_hvh[eloc][ihalf * 8];

    // ---------------- K pass ----------------
    {
        f32x4 o0 = {0.f, 0.f, 0.f, 0.f}, a1 = o0, ax = o0, ay = o0, az = o0;
#pragma unroll
        for (int t = 0; t < 8; ++t) {
            _Float16 hs = HK[t];
            half8 B0 = wfrag[(0 * 8 + t) * 64 + lane];
            half8 B1 = wfrag[(1 * 8 + t) * 64 + lane];
            half8 B2 = wfrag[(2 * 8 + t) * 64 + lane];
            half8 B3 = wfrag[(3 * 8 + t) * 64 + lane];
            half8 A0 = vmul(X0, hs);
            half8 As = vmul(XS, hs);
            half8 Aa = vmul(Xa, hs);
            half8 Ab = vmul(Xb, hs);
            half8 Ac = vmul(Xc, hs);
            o0 = __builtin_amdgcn_mfma_f32_16x16x32_f16(A0, B0, o0, 0, 0, 0);
            o0 = __builtin_amdgcn_mfma_f32_16x16x32_f16(As, B1, o0, 0, 0, 0);
            a1 = __builtin_amdgcn_mfma_f32_16x16x32_f16(A0, B2, a1, 0, 0, 0);
            ax = __builtin_amdgcn_mfma_f32_16x16x32_f16(Aa, B3, ax, 0, 0, 0);
            ay = __builtin_amdgcn_mfma_f32_16x16x32_f16(Ab, B3, ay, 0, 0, 0);
            az = __builtin_amdgcn_mfma_f32_16x16x32_f16(Ac, B3, az, 0, 0, 0);
        }
        const int j = m;
#pragma unroll
        for (int r = 0; r < 4; ++r) {
            const int el = eb + quad * 4 + r;
            const int e = e0 + el;
            const int dst = edst[e];
            float sh0 = s_sh[el][0], sh1 = s_sh[el][1], sh2 = s_sh[el][2];
            float k1x = a1[r] * sh0 + ax[r];
            float k1y = a1[r] * sh1 + ay[r];
            float k1z = a1[r] * sh2 + az[r];
            float dp = qd0[dst * 16 + j] * o0[r]
                     + qd1[0 * 131072 + dst * 16 + j] * k1x
                     + qd1[1 * 131072 + dst * 16 + j] * k1y
                     + qd1[2 * 131072 + dst * 16 + j] * k1z;
            dp += __shfl_xor(dp, 1);
            dp += __shfl_xor(dp, 2);
            dp += __shfl_xor(dp, 4);
            dp += __shfl_xor(dp, 8);
            if (j == 0) {
                float ev = s_sh[el][3] * expf(dp);
                int slot = atomicAdd(cursor + dst, 1);
                s_slot[el] = slot;
                expbuf[slot] = ev;
            }
        }
    }

    // ---------------- V pass ----------------
    {
        f32x4 o0 = {0.f, 0.f, 0.f, 0.f}, a1 = o0, ax = o0, ay = o0, az = o0;
        const half8* wfv = wfrag + 32 * 64;
#pragma unroll
        for (int t = 0; t < 8; ++t) {
            _Float16 hs = HV[t];
            half8 B0 = wfv[(0 * 8 + t) * 64 + lane];
            half8 B1 = wfv[(1 * 8 + t) * 64 + lane];
            half8 B2 = wfv[(2 * 8 + t) * 64 + lane];
            half8 B3 = wfv[(3 * 8 + t) * 64 + lane];
            half8 A0 = vmul(X0, hs);
            half8 As = vmul(XS, hs);
            half8 Aa = vmul(Xa, hs);
            half8 Ab = vmul(Xb, hs);
            half8 Ac = vmul(Xc, hs);
            o0 = __builtin_amdgcn_mfma_f32_16x16x32_f16(A0, B0, o0, 0, 0, 0);
            o0 = __builtin_amdgcn_mfma_f32_16x16x32_f16(As, B1, o0, 0, 0, 0);
            a1 = __builtin_amdgcn_mfma_f32_16x16x32_f16(A0, B2, a1, 0, 0, 0);
            ax = __builtin_amdgcn_mfma_f32_16x16x32_f16(Aa, B3, ax, 0, 0, 0);
            ay = __builtin_amdgcn_mfma_f32_16x16x32_f16(Ab, B3, ay, 0, 0, 0);
            az = __builtin_amdgcn_mfma_f32_16x16x32_f16(Ac, B3, az, 0, 0, 0);
        }
        const int j = m;
#pragma unroll
        for (int r = 0; r < 4; ++r) {
            const int el = eb + quad * 4 + r;
            float sh0 = s_sh[el][0], sh1 = s_sh[el][1], sh2 = s_sh[el][2];
            s_vt[el][j] = (_Float16)o0[r];
            s_vt[el][16 + j * 3 + 0] = (_Float16)(a1[r] * sh0 + ax[r]);
            s_vt[el][16 + j * 3 + 1] = (_Float16)(a1[r] * sh1 + ay[r]);
            s_vt[el][16 + j * 3 + 2] = (_Float16)(a1[r] * sh2 + az[r]);
        }
    }
    __syncthreads();

    // Coalesced slot-ordered writeout: 64 rows x 128B; 8 lanes per row.
#pragma unroll
    for (int pass = 0; pass < 2; ++pass) {
        int row = pass * 32 + (tid >> 3);
        int part = tid & 7;
        half8 val = *(const half8*)&s_vt[row][part * 8];
        int slot = s_slot[row];
        *(half8*)(vh + (size_t)slot * 64 + part * 8) = val;
    }
}

// k_out: per-node gather over slot-contiguous CSR range; z computed inline.
__global__ __launch_bounds__(256) void k_out(
    const int* __restrict__ rowptr,
    const float* __restrict__ expbuf, const _Float16* __restrict__ vh,
    float* __restrict__ fout) {
    const int col = threadIdx.x & 63;
    const int n = blockIdx.x * 4 + (threadIdx.x >> 6);
    const int s0 = rowptr[n], s1 = rowptr[n + 1];
    float zs = 0.f;
    for (int p = s0 + col; p < s1; p += 64) zs += expbuf[p];
#pragma unroll
    for (int off = 32; off > 0; off >>= 1) zs += __shfl_xor(zs, off);
    float zinv = zs > 0.f ? 1.f / zs : 0.f;
    float acc = 0.f;
    for (int p = s0; p < s1; ++p) {
        float ev = expbuf[p];
        float s = ev > 0.f ? sqrtf(ev * zinv) : 0.f;
        acc += s * (float)vh[(size_t)p * 64 + col];
    }
    fout[n * 64 + col] = acc;
}

extern "C" void kernel_launch(void* const* d_in, const int* in_sizes, int n_in,
                              void* d_out, int out_size, void* d_ws, size_t ws_size,
                              hipStream_t stream) {
    const float* f_in = (const float*)d_in[0];
    const float* evec = (const float*)d_in[1];
    const int* esrc = (const int*)d_in[2];
    const int* edst = (const int*)d_in[3];
    const float* Wq0 = (const float*)d_in[4];
    const float* Wq1 = (const float*)d_in[5];
    const float* Wk1 = (const float*)d_in[6];
    const float* Wk2 = (const float*)d_in[7];
    const float* Wv1 = (const float*)d_in[8];
    const float* Wv2 = (const float*)d_in[9];
    const float* Wd0 = (const float*)d_in[10];
    const float* Wd1 = (const float*)d_in[11];

    float* ws     = (float*)d_ws;
    int*   cnt    = (int*)(ws + CNT_OFF);
    int*   rowptr = (int*)(ws + RP_OFF);
    half8* wfrag  = (half8*)(ws + WF_OFF);
    float* qd0    = ws + QD0_OFF;
    float* qd1    = ws + QD1_OFF;
    float* expb   = ws + EXP_OFF;
    _Float16* vh  = (_Float16*)(ws + VH_OFF);
    float* fout   = (float*)d_out;

    hipMemsetAsync(cnt, 0, (size_t)8192 * sizeof(int), stream);

    k_prep<<<592, 256, 0, stream>>>(f_in, Wq0, Wq1, Wd0, Wd1, Wk2, Wv2, edst,
                                    wfrag, qd0, qd1, cnt);
    k_scan<<<1, 1024, 0, stream>>>(cnt, rowptr);
    k_edge<<<N_EDGES / 64, 256, 0, stream>>>(f_in, evec, esrc, edst, Wk1, Wv1,
                                             wfrag, qd0, qd1, cnt, expb, vh);
    k_out<<<N_NODES / 4, 256, 0, stream>>>(rowptr, expb, vh, fout);
}